// Round 14
// baseline (197.031 us; speedup 1.0000x reference)
//
#include <hip/hip_runtime.h>
#include <math.h>
#include <stdint.h>

typedef _Float16 half8v __attribute__((ext_vector_type(8)));
typedef _Float16 half4v __attribute__((ext_vector_type(4)));
typedef _Float16 half2v __attribute__((ext_vector_type(2)));
typedef __fp16 fp16x2 __attribute__((ext_vector_type(2)));
typedef float floatx4 __attribute__((ext_vector_type(4)));

#define MFMA16(a, b, c) __builtin_amdgcn_mfma_f32_16x16x32_f16(a, b, c, 0, 0, 0)

// Q pre-scale: 1/sqrt(64) * log2(e), folded so attention uses exp2 directly.
#define QSCALE 0.18033688011112f

// Async global->LDS, 16B per lane. LDS dest must be wave-uniform base + lane*16;
// the GLOBAL source address is per-lane arbitrary (it's a gather).
__device__ __forceinline__ void gld_lds16(const void* g, void* l) {
  __builtin_amdgcn_global_load_lds(
      (const __attribute__((address_space(1))) uint32_t*)(uintptr_t)g,
      (__attribute__((address_space(3))) uint32_t*)(uintptr_t)l, 16, 0, 0);
}

// Packed f32x2 -> f16x2 (rtz), bit-cast to our _Float16 vector type.
__device__ __forceinline__ half2v pk16(float a, float b) {
  fp16x2 t = __builtin_amdgcn_cvt_pkrtz(a, b);
  return __builtin_bit_cast(half2v, t);
}

// LDS bank swizzle for 64-col fp16 tiles (128B rows), 16B blocks.
__device__ __forceinline__ int swz(int row, int blk) {
  return row * 64 + ((blk ^ (row & 7)) << 3);
}

// LDS bank swizzle for 32-col fp16 tiles (64B rows = 16 banks): XOR chunk
// with (row>>1)&3 so 16-row b128 frag reads are 2-way, not 8-way.
__device__ __forceinline__ int vswz(int row, int blk) {
  return row * 32 + ((blk ^ ((row >> 1) & 3)) << 3);
}

// GEMM 32-col tile swizzle (same math as vswz; kept separate for clarity).
__device__ __forceinline__ int gswz(int row, int blk) {
  return row * 32 + ((blk ^ ((row >> 1) & 3)) << 3);
}

// ---------------------------------------------------------------------------
// Prep (fused): blocks 0..2047 convert X fp32->fp16; blocks 2048..3071
// transpose+convert the weights.  (unchanged)
// ---------------------------------------------------------------------------
__global__ __launch_bounds__(256) void prep(
    const float* __restrict__ X, const float* __restrict__ Wq,
    const float* __restrict__ Wkv, const float* __restrict__ Wo,
    _Float16* __restrict__ X16, _Float16* __restrict__ WqkvT,
    _Float16* __restrict__ WoT)
{
  __shared__ alignas(16) _Float16 Tt[64 * 68];
  const int bid = blockIdx.x;
  if (bid < 2048) {
    size_t gid = (size_t)bid * 256 + threadIdx.x;
    const float4* src = (const float4*)(X) + gid * 2;
    float4 a = src[0], b = src[1];
    half8v h;
    h[0]=(_Float16)a.x; h[1]=(_Float16)a.y; h[2]=(_Float16)a.z; h[3]=(_Float16)a.w;
    h[4]=(_Float16)b.x; h[5]=(_Float16)b.y; h[6]=(_Float16)b.z; h[7]=(_Float16)b.w;
    *((half8v*)X16 + gid) = h;
    return;
  }
  int b = bid - 2048;
  const float* src; _Float16* dst; int N, tk, tn;
  if (b < 256)      { src = Wq;  dst = WqkvT;                 N = 1024; tk = b & 15;        tn = b >> 4; }
  else if (b < 768) { src = Wkv; dst = WqkvT + (size_t)1024 * 1024; N = 2048; tk = (b - 256) & 15; tn = (b - 256) >> 4; }
  else              { src = Wo;  dst = WoT;                   N = 1024; tk = (b - 768) & 15; tn = (b - 768) >> 4; }

  const int t = threadIdx.x;
  {
    int kg = t >> 4, ng = t & 15;
    const float* sp = src + (size_t)(tk * 64 + kg * 4) * N + tn * 64 + ng * 4;
    float4 r0 = *(const float4*)(sp);
    float4 r1 = *(const float4*)(sp + N);
    float4 r2 = *(const float4*)(sp + 2 * N);
    float4 r3 = *(const float4*)(sp + 3 * N);
    half4v h;
    h[0]=(_Float16)r0.x; h[1]=(_Float16)r1.x; h[2]=(_Float16)r2.x; h[3]=(_Float16)r3.x;
    *(half4v*)&Tt[(ng * 4 + 0) * 68 + kg * 4] = h;
    h[0]=(_Float16)r0.y; h[1]=(_Float16)r1.y; h[2]=(_Float16)r2.y; h[3]=(_Float16)r3.y;
    *(half4v*)&Tt[(ng * 4 + 1) * 68 + kg * 4] = h;
    h[0]=(_Float16)r0.z; h[1]=(_Float16)r1.z; h[2]=(_Float16)r2.z; h[3]=(_Float16)r3.z;
    *(half4v*)&Tt[(ng * 4 + 2) * 68 + kg * 4] = h;
    h[0]=(_Float16)r0.w; h[1]=(_Float16)r1.w; h[2]=(_Float16)r2.w; h[3]=(_Float16)r3.w;
    *(half4v*)&Tt[(ng * 4 + 3) * 68 + kg * 4] = h;
  }
  __syncthreads();
  #pragma unroll
  for (int i = 0; i < 2; i++) {
    int idx = t + i * 256;
    int nl = idx >> 3, k8 = (idx & 7) * 8;
    half8v v = *(half8v*)&Tt[nl * 68 + k8];
    *(half8v*)(dst + (size_t)(tn * 64 + nl) * 1024 + tk * 64 + k8) = v;
  }
}

// ---------------------------------------------------------------------------
// Kernel 1: QKV projection (m97 structure + gswz, BK=32) + T1 XCD swizzle
// (bijective 768=8*96; bx-major -> 3 A-panels L2-resident per XCD).
// ---------------------------------------------------------------------------
__global__ __launch_bounds__(256) void qkv_gemm(
    const _Float16* __restrict__ X16, const _Float16* __restrict__ WqkvT,
    _Float16* __restrict__ q_ws, _Float16* __restrict__ k_ws,
    _Float16* __restrict__ vT_ws)
{
  constexpr int K = 1024;
  __shared__ alignas(16) _Float16 Tt[128 * 136];
  _Float16* As = Tt;
  _Float16* Bs = Tt + 4096;

  const int id = blockIdx.y * 32 + blockIdx.x;
  const int w  = (id & 7) * 96 + (id >> 3);   // XCD-contiguous work id
  const int m0 = (w / 24) * 128;
  const int n0 = (w % 24) * 128;

  const int tid  = threadIdx.x;
  const int wave = tid >> 6, lane = tid & 63;
  const int qd = lane >> 4, l15 = lane & 15;
  const int wr = (wave >> 1) * 64, wc = (wave & 1) * 64;
  const int r0i = tid >> 2;
  const int cbs = (((tid & 3) ^ ((r0i >> 1) & 3))) * 8;

  floatx4 acc[4][4] = {};

  for (int k0 = 0; k0 < K; k0 += 32) {
    gld_lds16(X16 + (size_t)(m0 + r0i) * K + k0 + cbs, &As[tid * 8]);
    gld_lds16(X16 + (size_t)(m0 + 64 + r0i) * K + k0 + cbs, &As[(tid + 256) * 8]);
    gld_lds16(WqkvT + (size_t)(n0 + r0i) * K + k0 + cbs, &Bs[tid * 8]);
    gld_lds16(WqkvT + (size_t)(n0 + 64 + r0i) * K + k0 + cbs, &Bs[(tid + 256) * 8]);
    __syncthreads();
    half8v a[4], b[4];
    #pragma unroll
    for (int it = 0; it < 4; it++)
      a[it] = *(half8v*)&As[gswz(wr + it * 16 + l15, qd)];
    #pragma unroll
    for (int jt = 0; jt < 4; jt++)
      b[jt] = *(half8v*)&Bs[gswz(wc + jt * 16 + l15, qd)];
    #pragma unroll
    for (int it = 0; it < 4; it++)
      #pragma unroll
      for (int jt = 0; jt < 4; jt++)
        acc[it][jt] = MFMA16(a[it], b[jt], acc[it][jt]);
    __syncthreads();
  }

  if (n0 < 2048) {
    #pragma unroll
    for (int it = 0; it < 4; it++) {
      #pragma unroll
      for (int jt = 0; jt < 4; jt++) {
        #pragma unroll
        for (int r = 0; r < 4; r++) {
          int m = m0 + wr + it * 16 + qd * 4 + r;
          int n = n0 + wc + jt * 16 + l15;
          float val = acc[it][jt][r];
          int bb = m >> 11, nn = m & 2047;
          if (n0 < 1024) {
            int h = n >> 6, d = n & 63;
            q_ws[(((size_t)bb * 16 + h) * 2048 + nn) * 64 + d] = (_Float16)(val * QSCALE);
          } else {
            int c = n - 1024, h = c >> 6, d = c & 63;
            k_ws[(((size_t)bb * 16 + h) * 2048 + nn) * 64 + d] = (_Float16)val;
          }
        }
      }
    }
  } else {
    #pragma unroll
    for (int it = 0; it < 4; it++) {
      #pragma unroll
      for (int jt = 0; jt < 4; jt++) {
        #pragma unroll
        for (int r = 0; r < 4; r++) {
          int ml = wr + it * 16 + qd * 4 + r;
          int nl = wc + jt * 16 + l15;
          Tt[nl * 136 + ml] = (_Float16)acc[it][jt][r];
        }
      }
    }
    __syncthreads();
    int row = tid >> 1;
    int mh  = (tid & 1) * 64;
    int c   = (n0 - 2048) + row;
    int bb  = m0 >> 11;
    int nnb = (m0 & 2047) + mh;
    _Float16* dstp =
        vT_ws + (((size_t)bb * 16 + (c >> 6)) * 64 + (c & 63)) * 2048 + nnb;
    #pragma unroll
    for (int i = 0; i < 8; i++)
      *(half8v*)(dstp + i * 8) = *(half8v*)&Tt[row * 136 + mh + i * 8];
  }
}

// ---------------------------------------------------------------------------
// Kernel 2: flash attention v18 — v17 + K-fragment register pre-read.
// kf(i+1) is ds_read into registers at the END of sm_pv(i), hidden under
// the PV MFMAs (K(i+1) is LDS-resident a full phase earlier thanks to the
// dbuf + counted-vmcnt ledger). qk(i) then starts MFMAs immediately: the
// ~120cy kf ds_read latency leaves the serial chain. Ledger (4 glds/stage,
// issue order: prologue Q,K0,K1,V0; qk(i) issues K(i+2) [i<=13]; sm_pv(i)
// issues V(i+1) [i<=14]):
//   steady state: every wait is vmcnt(12), retiring exactly the needed
//   oldest group (K or V); tail: sm_pv(14) V=8/K=8, sm_pv(15) V=4,
//   sm_pv(16) V=0. kfA/kfB alternate with sA/sB (manual 2x unroll).
// ---------------------------------------------------------------------------
__global__ __launch_bounds__(256, 2) void attn_kernel(
    const _Float16* __restrict__ q_ws, const _Float16* __restrict__ k_ws,
    const _Float16* __restrict__ vT_ws, _Float16* __restrict__ aout)
{
  constexpr int N = 2048;
  // 80KB: K [4w][2][2048] 32KB | V [4w][2][2048] 32KB | PQ [4w][2048] 16KB
  // Epilogue overlay: sc [4][64][64] f32 = 64KB at base; ls_sc 1KB at 65536.
  __shared__ alignas(16) char smem[81920];
  _Float16* Kbase = (_Float16*)smem;                  // 32KB
  _Float16* Vbase = (_Float16*)(smem + 32768);        // 32KB
  _Float16* PQ    = (_Float16*)(smem + 65536);        // 16KB

  const int id = blockIdx.x;
  const int bh = ((id >> 8) << 3) | (id & 7);
  const int qt = (id >> 3) & 31;

  const _Float16* Qp = q_ws + (size_t)bh * N * 64;
  const _Float16* Kp = k_ws + (size_t)bh * N * 64;
  const _Float16* Vp = vT_ws + (size_t)bh * 64 * N;

  const int tid = threadIdx.x, wave = tid >> 6, lane = tid & 63;
  const int qd = lane >> 4, l15 = lane & 15;
  const int q0 = qt * 64;
  const int wkv = wave * 32;        // this wave's kv offset within a stride

  _Float16* Ps = PQ + wave * 2048;          // private P slot (4KB)

  // per-wave staging lane constants
  const int krr = lane >> 3, kcb = (lane & 7) ^ krr;               // K staging
  const int vrr = lane >> 2, vcb = (lane & 3) ^ ((lane >> 3) & 3); // V staging

  auto stage_k = [&](int il, int buf) {
    const _Float16* src = Kp + (size_t)(wkv + il * 128) * 64;
    _Float16* dst = Kbase + (wave * 2 + buf) * 2048;
    #pragma unroll
    for (int j = 0; j < 4; j++)
      gld_lds16(src + (size_t)(j * 8 + krr) * 64 + kcb * 8,
                dst + (j * 64 + lane) * 8);
  };
  auto stage_v = [&](int il, int buf) {
    const _Float16* src = Vp + wkv + il * 128;
    _Float16* dst = Vbase + (wave * 2 + buf) * 2048;
    #pragma unroll
    for (int j = 0; j < 4; j++)
      gld_lds16(src + (size_t)(j * 16 + vrr) * N + vcb * 8,
                dst + (j * 64 + lane) * 8);
  };
  auto kf_preread = [&](int i, half8v (&kf)[2][2]) {
    const _Float16* Kb = Kbase + (wave * 2 + (i & 1)) * 2048;
    #pragma unroll
    for (int ks = 0; ks < 2; ks++) {
      kf[ks][0] = *(half8v*)&Kb[swz(l15, ks * 4 + qd)];
      kf[ks][1] = *(half8v*)&Kb[swz(16 + l15, ks * 4 + qd)];
    }
  };

  // Prologue (issue order: Q, K0, K1, V0 — the ledger depends on it).
  #pragma unroll
  for (int i = 0; i < 2; i++) {
    int idx = tid + i * 256;
    int r = idx >> 3, cb = (idx ^ r) & 7;
    gld_lds16(Qp + (size_t)(q0 + r) * 64 + cb * 8, PQ + idx * 8);
  }
  stage_k(0, 0);
  stage_k(1, 1);
  stage_v(0, 0);

  asm volatile("s_waitcnt vmcnt(12)" ::: "memory");   // own Q portion done
  __builtin_amdgcn_s_barrier();                       // Q resident (all waves)
  __builtin_amdgcn_sched_barrier(0);

  half8v qf[4][2];
  #pragma unroll
  for (int m = 0; m < 4; m++)
    #pragma unroll
    for (int ks = 0; ks < 2; ks++)
      qf[m][ks] = *(half8v*)&PQ[swz(m * 16 + l15, ks * 4 + qd)];

  asm volatile("s_waitcnt lgkmcnt(0)" ::: "memory");  // qf in regs
  __builtin_amdgcn_s_barrier();                       // before P overwrites Q
  __builtin_amdgcn_sched_barrier(0);

  const half8v ones = {(_Float16)1, (_Float16)1, (_Float16)1, (_Float16)1,
                       (_Float16)1, (_Float16)1, (_Float16)1, (_Float16)1};
  floatx4 o[4][4] = {};
  floatx4 ol[4] = {};
  floatx4 sA[2][4], sB[2][4];
  half8v kfA[2][2], kfB[2][2];

  // QK phase: kf already in regs; lgkm-drain pre-reads, refill K(i+2), MFMA.
  auto qk_step = [&](int i, floatx4 (&scur)[2][4], half8v (&kf)[2][2]) {
    asm volatile("s_waitcnt lgkmcnt(0)" ::: "memory");  // kf pre-reads done
    __builtin_amdgcn_sched_barrier(0);
    if (i <= 13) stage_k(i + 2, i & 1);   // WAR-safe: kf reads drained
    __builtin_amdgcn_sched_barrier(0);
    #pragma unroll
    for (int nt = 0; nt < 2; nt++)
      #pragma unroll
      for (int m = 0; m < 4; m++)
        scur[nt][m] = floatx4{0.f, 0.f, 0.f, 0.f};
    __builtin_amdgcn_s_setprio(1);
    #pragma unroll
    for (int ks = 0; ks < 2; ks++)
      #pragma unroll
      for (int m = 0; m < 4; m++) {
        scur[0][m] = MFMA16(kf[ks][0], qf[m][ks], scur[0][m]);
        scur[1][m] = MFMA16(kf[ks][1], qf[m][ks], scur[1][m]);
      }
    __builtin_amdgcn_s_setprio(0);
  };

  // SM+PV for tile i-1; pre-reads kf(i+1) into kfn after the PV MFMAs.
  auto sm_pv_step = [&](int i, floatx4 (&sprev)[2][4], half8v (&kfn)[2][2]) {
    #pragma unroll
    for (int m = 0; m < 4; m++)
      #pragma unroll
      for (int nt = 0; nt < 2; nt++) {
        float p0 = __builtin_amdgcn_exp2f(sprev[nt][m][0]);
        float p1 = __builtin_amdgcn_exp2f(sprev[nt][m][1]);
        float p2 = __builtin_amdgcn_exp2f(sprev[nt][m][2]);
        float p3 = __builtin_amdgcn_exp2f(sprev[nt][m][3]);
        half2v h01 = pk16(p0, p1);
        half2v h23 = pk16(p2, p3);
        half4v pk;
        pk[0] = h01[0]; pk[1] = h01[1]; pk[2] = h23[0]; pk[3] = h23[1];
        *(half4v*)&Ps[vswz(m * 16 + l15, 2 * nt + (qd >> 1)) + (qd & 1) * 4] = pk;
      }
    half8v pf[4], vfr[4];
    #pragma unroll
    for (int m = 0; m < 4; m++)
      pf[m] = *(half8v*)&Ps[vswz(m * 16 + l15, qd)];
    // V(i-1) wait.
    if (i <= 13)       asm volatile("s_waitcnt vmcnt(12)" ::: "memory");
    else if (i == 14)  asm volatile("s_waitcnt vmcnt(8)"  ::: "memory");
    else if (i == 15)  asm volatile("s_waitcnt vmcnt(4)"  ::: "memory");
    else               asm volatile("s_waitcnt vmcnt(0)"  ::: "memory");
    __builtin_amdgcn_sched_barrier(0);
    const _Float16* Vb = Vbase + (wave * 2 + ((i - 1) & 1)) * 2048;
    #pragma unroll
    for (int dt = 0; dt < 4; dt++)
      vfr[dt] = *(half8v*)&Vb[vswz(dt * 16 + l15, qd)];
    asm volatile("s_waitcnt lgkmcnt(0)" ::: "memory");  // reads done (WAR)
    __builtin_amdgcn_sched_barrier(0);
    if (i <= 14) stage_v(i + 1, (i + 1) & 1);
    __builtin_amdgcn_sched_barrier(0);
    __builtin_amdgcn_s_setprio(1);
    #pragma unroll
    for (int m = 0; m < 4; m++)
      ol[m] = MFMA16(pf[m], ones, ol[m]);
    #pragma unroll
    for (int m = 0; m < 4; m++)
      #pragma unroll
      for (int dt = 0; dt < 4; dt++)
        o[m][dt] = MFMA16(pf[m], vfr[dt], o[m][dt]);
    __builtin_amdgcn_s_setprio(0);
    // kf(i+1) pre-read (hidden under next phase; drained at next qk).
    if (i <= 14) {
      if (i <= 13) asm volatile("s_waitcnt vmcnt(12)" ::: "memory");
      else         asm volatile("s_waitcnt vmcnt(8)"  ::: "memory");
      __builtin_amdgcn_sched_barrier(0);
      kf_preread(i + 1, kfn);
    }
  };

  // Peel: kf0 pre-read, QK(0), V1 issue, kf1 pre-read.
  asm volatile("s_waitcnt vmcnt(8)" ::: "memory");   // K0 landed ([K1,V0]=8)
  __builtin_amdgcn_sched_barrier(0);
  kf_preread(0, kfA);
  qk_step(0, sA, kfA);
  stage_v(1, 1);
  asm volatile("s_waitcnt vmcnt(12)" ::: "memory");  // K1 landed
  __builtin_amdgcn_sched_barrier(0);
  kf_preread(1, kfB);

  // iters 1..15, paired so s/kf arrays alternate without copies.
  for (int i = 1; i <= 15; i += 2) {
    qk_step(i, sB, kfB);
    sm_pv_step(i, sA, kfA);        // pre-reads kf(i+1) into kfA
    if (i + 1 <= 15) {
      qk_step(i + 1, sA, kfA);
      sm_pv_step(i + 1, sB, kfB);  // pre-reads kf(i+2) into kfB
    }
  }
  // tail: softmax+PV of tile 15 (held in sB since 15 is odd).
  sm_pv_step(16, sB, kfA);

  // ---- epilogue: cross-wave reduction of O and lsum via (dead) LDS ----
  __syncthreads();
  float* sc    = (float*)smem;            // [4][64][64] f32 partials (64KB)
  float* ls_sc = (float*)(smem + 65536);  // [4][64] f32 lsums (1KB)
  float* myp = sc + wave * 4096;
  #pragma unroll
  for (int m = 0; m < 4; m++)
    #pragma unroll
    for (int r = 0; r < 4; r++) {
      int row = m * 16 + qd * 4 + r;
      myp[row * 64 +  0 + l15] = o[m][0][r];
      myp[row * 64 + 16 + l15] = o[m][1][r];
      myp[row * 64 + 32 + l15] = o[m][2][r];
      myp[row * 64 + 48 + l15] = o[m][3][r];
      ls_sc[wave * 64 + row] = ol[m][r];  // same value from 16 lanes, one wins
    }
  __syncthreads();

  const int bb = bh >> 4, hh = bh & 15;
  #pragma unroll
  for (int j = 0; j < 4; j++) {
    int row = wave * 16 + j * 4 + qd;
    floatx4 a0 = *(floatx4*)&sc[(size_t)(0 * 64 + row) * 64 + l15 * 4];
    floatx4 a1 = *(floatx4*)&sc[(size_t)(1 * 64 + row) * 64 + l15 * 4];
    floatx4 a2 = *(floatx4*)&sc[(size_t)(2 * 64 + row) * 64 + l15 * 4];
    floatx4 a3 = *(floatx4*)&sc[(size_t)(3 * 64 + row) * 64 + l15 * 4];
    floatx4 sum = (a0 + a1) + (a2 + a3);
    float ls = ls_sc[row] + ls_sc[64 + row] + ls_sc[128 + row] + ls_sc[192 + row];
    float inv = 1.0f / ls;
    half2v h01 = pk16(sum[0] * inv, sum[1] * inv);
    half2v h23 = pk16(sum[2] * inv, sum[3] * inv);
    half4v hv;
    hv[0] = h01[0]; hv[1] = h01[1]; hv[2] = h23[0]; hv[3] = h23[1];
    *(half4v*)(aout + ((size_t)(bb * 2048 + q0 + row)) * 1024 + hh * 64 + l15 * 4) = hv;
  }
}

// ---------------------------------------------------------------------------
// Kernel 3: out projection — BK=64 + T1 XCD swizzle (bijective 512=8*64).
// ---------------------------------------------------------------------------
__global__ __launch_bounds__(256) void out_gemm(
    const _Float16* __restrict__ A, const _Float16* __restrict__ WoT,
    const float* __restrict__ bo, float* __restrict__ Out)
{
  constexpr int K = 1024;
  __shared__ alignas(16) _Float16 As[64 * 64];    // 8 KB
  __shared__ alignas(16) _Float16 Bs[128 * 64];   // 16 KB

  const int id = blockIdx.y * 64 + blockIdx.x;
  const int w  = (id & 7) * 64 + (id >> 3);   // XCD-contiguous work id
  const int m0 = (w >> 3) * 64;
  const int n0 = (w & 7) * 128;
  const int tid = threadIdx.x;
  const int wave = tid >> 6, lane = tid & 63;
  const int qd = lane >> 4, l15 = lane & 15;
  const int wr = (wave >> 1) * 32, wc = (wave & 1) * 64;

  floatx4 acc[2][4] = {};

  for (int k0 = 0; k0 < K; k0 += 64) {
    #pragma unroll
    for (int i = 0; i < 2; i++) {
      int idx = tid + i * 256;
      int r = idx >> 3, cb = (idx ^ r) & 7;
      gld_lds16(A + (size_t)(m0 + r) * K + k0 + cb * 8, &As[idx * 8]);
    }
    #pragma unroll
    for (int i = 0; i < 4; i++) {
      int idx = tid + i * 256;
      int r = idx >> 3, cb = (idx ^ r) & 7;
      gld_lds16(WoT + (size_t)(n0 + r) * K + k0 + cb * 8, &Bs[idx * 8]);
    }
    __syncthreads();
    half8v a[2][2], b[4][2];
    #pragma unroll
    for (int it = 0; it < 2; it++)
      #pragma unroll
      for (int ks = 0; ks < 2; ks++)
        a[it][ks] = *(half8v*)&As[swz(wr + it * 16 + l15, ks * 4 + qd)];
    #pragma unroll
    for (int jt = 0; jt < 4; jt++)
      #pragma unroll
      for (int ks = 0; ks < 2; ks++)
        b[jt][ks] = *(half8v*)&Bs[swz(wc + jt * 16 + l15, ks * 4 + qd)];
    #pragma unroll
    for (int ks = 0; ks < 2; ks++)
      #pragma unroll
      for (int it = 0; it < 2; it++)
        #pragma unroll
        for (int jt = 0; jt < 4; jt++)
          acc[it][jt] = MFMA16(a[it][ks], b[jt][ks], acc[it][jt]);
    __syncthreads();
  }

  #pragma unroll
  for (int it = 0; it < 2; it++) {
    #pragma unroll
    for (int jt = 0; jt < 4; jt++) {
      int n = n0 + wc + jt * 16 + l15;
      float bias = bo[n];
      #pragma unroll
      for (int r = 0; r < 4; r++) {
        int m = m0 + wr + it * 16 + qd * 4 + r;
        Out[(size_t)m * 1024 + n] = acc[it][jt][r] + bias;
      }
    }
  }
}

// ---------------------------------------------------------------------------
extern "C" void kernel_launch(void* const* d_in, const int* in_sizes, int n_in,
                              void* d_out, int out_size, void* d_ws, size_t ws_size,
                              hipStream_t stream) {
  const float* X   = (const float*)d_in[0];
  const float* Wq  = (const float*)d_in[1];
  const float* Wkv = (const float*)d_in[2];
  const float* Wo  = (const float*)d_in[3];
  const float* bo  = (const float*)d_in[4];
  float* out = (float*)d_out;

  const size_t M4 = (size_t)4 * 1024 * 1024;
  _Float16* q_ws   = (_Float16*)d_ws;
  _Float16* k_ws   = q_ws + M4;
  _Float16* vT_ws  = k_ws + M4;
  _Float16* X16    = vT_ws + M4;
  _Float16* WqkvT  = X16 + M4;
  _Float16* WoT    = WqkvT + (size_t)3 * 1024 * 1024;
  _Float16* aout   = X16;  // X16 dead after qkv_gemm

  prep<<<3072, 256, 0, stream>>>(X, Wq, Wkv, Wo, X16, WqkvT, WoT);
  qkv_gemm<<<dim3(32, 24), 256, 0, stream>>>(X16, WqkvT, q_ws, k_ws, vT_ws);
  attn_kernel<<<1024, 256, 0, stream>>>(q_ws, k_ws, vT_ws, aout);
  out_gemm<<<dim3(64, 8), 256, 0, stream>>>(aout, WoT, bo, out);
}

// Round 15
// 176.461 us; speedup vs baseline: 1.1166x; 1.1166x over previous
//
#include <hip/hip_runtime.h>
#include <math.h>
#include <stdint.h>

typedef _Float16 half8v __attribute__((ext_vector_type(8)));
typedef _Float16 half4v __attribute__((ext_vector_type(4)));
typedef _Float16 half2v __attribute__((ext_vector_type(2)));
typedef __fp16 fp16x2 __attribute__((ext_vector_type(2)));
typedef float floatx4 __attribute__((ext_vector_type(4)));

#define MFMA16(a, b, c) __builtin_amdgcn_mfma_f32_16x16x32_f16(a, b, c, 0, 0, 0)

// Q pre-scale: 1/sqrt(64) * log2(e), folded so attention uses exp2 directly.
#define QSCALE 0.18033688011112f

// Async global->LDS, 16B per lane. LDS dest must be wave-uniform base + lane*16;
// the GLOBAL source address is per-lane arbitrary (it's a gather).
__device__ __forceinline__ void gld_lds16(const void* g, void* l) {
  __builtin_amdgcn_global_load_lds(
      (const __attribute__((address_space(1))) uint32_t*)(uintptr_t)g,
      (__attribute__((address_space(3))) uint32_t*)(uintptr_t)l, 16, 0, 0);
}

// Packed f32x2 -> f16x2 (rtz), bit-cast to our _Float16 vector type.
__device__ __forceinline__ half2v pk16(float a, float b) {
  fp16x2 t = __builtin_amdgcn_cvt_pkrtz(a, b);
  return __builtin_bit_cast(half2v, t);
}

// LDS bank swizzle for 64-col fp16 tiles (128B rows), 16B blocks.
__device__ __forceinline__ int swz(int row, int blk) {
  return row * 64 + ((blk ^ (row & 7)) << 3);
}

// LDS bank swizzle for 32-col fp16 tiles (64B rows = 16 banks): XOR chunk
// with (row>>1)&3 so 16-row b128 frag reads are 2-way, not 8-way.
__device__ __forceinline__ int vswz(int row, int blk) {
  return row * 32 + ((blk ^ ((row >> 1) & 3)) << 3);
}

// GEMM 32-col tile swizzle (same math as vswz; kept separate for clarity).
__device__ __forceinline__ int gswz(int row, int blk) {
  return row * 32 + ((blk ^ ((row >> 1) & 3)) << 3);
}

// ---------------------------------------------------------------------------
// Prep (fused): blocks 0..2047 convert X fp32->fp16; blocks 2048..3071
// transpose+convert the weights.  (unchanged)
// ---------------------------------------------------------------------------
__global__ __launch_bounds__(256) void prep(
    const float* __restrict__ X, const float* __restrict__ Wq,
    const float* __restrict__ Wkv, const float* __restrict__ Wo,
    _Float16* __restrict__ X16, _Float16* __restrict__ WqkvT,
    _Float16* __restrict__ WoT)
{
  __shared__ alignas(16) _Float16 Tt[64 * 68];
  const int bid = blockIdx.x;
  if (bid < 2048) {
    size_t gid = (size_t)bid * 256 + threadIdx.x;
    const float4* src = (const float4*)(X) + gid * 2;
    float4 a = src[0], b = src[1];
    half8v h;
    h[0]=(_Float16)a.x; h[1]=(_Float16)a.y; h[2]=(_Float16)a.z; h[3]=(_Float16)a.w;
    h[4]=(_Float16)b.x; h[5]=(_Float16)b.y; h[6]=(_Float16)b.z; h[7]=(_Float16)b.w;
    *((half8v*)X16 + gid) = h;
    return;
  }
  int b = bid - 2048;
  const float* src; _Float16* dst; int N, tk, tn;
  if (b < 256)      { src = Wq;  dst = WqkvT;                 N = 1024; tk = b & 15;        tn = b >> 4; }
  else if (b < 768) { src = Wkv; dst = WqkvT + (size_t)1024 * 1024; N = 2048; tk = (b - 256) & 15; tn = (b - 256) >> 4; }
  else              { src = Wo;  dst = WoT;                   N = 1024; tk = (b - 768) & 15; tn = (b - 768) >> 4; }

  const int t = threadIdx.x;
  {
    int kg = t >> 4, ng = t & 15;
    const float* sp = src + (size_t)(tk * 64 + kg * 4) * N + tn * 64 + ng * 4;
    float4 r0 = *(const float4*)(sp);
    float4 r1 = *(const float4*)(sp + N);
    float4 r2 = *(const float4*)(sp + 2 * N);
    float4 r3 = *(const float4*)(sp + 3 * N);
    half4v h;
    h[0]=(_Float16)r0.x; h[1]=(_Float16)r1.x; h[2]=(_Float16)r2.x; h[3]=(_Float16)r3.x;
    *(half4v*)&Tt[(ng * 4 + 0) * 68 + kg * 4] = h;
    h[0]=(_Float16)r0.y; h[1]=(_Float16)r1.y; h[2]=(_Float16)r2.y; h[3]=(_Float16)r3.y;
    *(half4v*)&Tt[(ng * 4 + 1) * 68 + kg * 4] = h;
    h[0]=(_Float16)r0.z; h[1]=(_Float16)r1.z; h[2]=(_Float16)r2.z; h[3]=(_Float16)r3.z;
    *(half4v*)&Tt[(ng * 4 + 2) * 68 + kg * 4] = h;
    h[0]=(_Float16)r0.w; h[1]=(_Float16)r1.w; h[2]=(_Float16)r2.w; h[3]=(_Float16)r3.w;
    *(half4v*)&Tt[(ng * 4 + 3) * 68 + kg * 4] = h;
  }
  __syncthreads();
  #pragma unroll
  for (int i = 0; i < 2; i++) {
    int idx = t + i * 256;
    int nl = idx >> 3, k8 = (idx & 7) * 8;
    half8v v = *(half8v*)&Tt[nl * 68 + k8];
    *(half8v*)(dst + (size_t)(tn * 64 + nl) * 1024 + tk * 64 + k8) = v;
  }
}

// ---------------------------------------------------------------------------
// Kernel 1: QKV projection (m97 structure + gswz, BK=32 — proven config)
// + T1 XCD-aware block swizzle (bijective 768=8*96; bx-major -> 3 A-panels
// L2-resident per XCD, reused 24x each).
// ---------------------------------------------------------------------------
__global__ __launch_bounds__(256) void qkv_gemm(
    const _Float16* __restrict__ X16, const _Float16* __restrict__ WqkvT,
    _Float16* __restrict__ q_ws, _Float16* __restrict__ k_ws,
    _Float16* __restrict__ vT_ws)
{
  constexpr int K = 1024;
  __shared__ alignas(16) _Float16 Tt[128 * 136];
  _Float16* As = Tt;
  _Float16* Bs = Tt + 4096;

  const int id = blockIdx.y * 32 + blockIdx.x;
  const int w  = (id & 7) * 96 + (id >> 3);   // XCD-contiguous work id
  const int m0 = (w / 24) * 128;
  const int n0 = (w % 24) * 128;

  const int tid  = threadIdx.x;
  const int wave = tid >> 6, lane = tid & 63;
  const int qd = lane >> 4, l15 = lane & 15;
  const int wr = (wave >> 1) * 64, wc = (wave & 1) * 64;
  const int r0i = tid >> 2;
  const int cbs = (((tid & 3) ^ ((r0i >> 1) & 3))) * 8;

  floatx4 acc[4][4] = {};

  for (int k0 = 0; k0 < K; k0 += 32) {
    gld_lds16(X16 + (size_t)(m0 + r0i) * K + k0 + cbs, &As[tid * 8]);
    gld_lds16(X16 + (size_t)(m0 + 64 + r0i) * K + k0 + cbs, &As[(tid + 256) * 8]);
    gld_lds16(WqkvT + (size_t)(n0 + r0i) * K + k0 + cbs, &Bs[tid * 8]);
    gld_lds16(WqkvT + (size_t)(n0 + 64 + r0i) * K + k0 + cbs, &Bs[(tid + 256) * 8]);
    __syncthreads();
    half8v a[4], b[4];
    #pragma unroll
    for (int it = 0; it < 4; it++)
      a[it] = *(half8v*)&As[gswz(wr + it * 16 + l15, qd)];
    #pragma unroll
    for (int jt = 0; jt < 4; jt++)
      b[jt] = *(half8v*)&Bs[gswz(wc + jt * 16 + l15, qd)];
    #pragma unroll
    for (int it = 0; it < 4; it++)
      #pragma unroll
      for (int jt = 0; jt < 4; jt++)
        acc[it][jt] = MFMA16(a[it], b[jt], acc[it][jt]);
    __syncthreads();
  }

  if (n0 < 2048) {
    #pragma unroll
    for (int it = 0; it < 4; it++) {
      #pragma unroll
      for (int jt = 0; jt < 4; jt++) {
        #pragma unroll
        for (int r = 0; r < 4; r++) {
          int m = m0 + wr + it * 16 + qd * 4 + r;
          int n = n0 + wc + jt * 16 + l15;
          float val = acc[it][jt][r];
          int bb = m >> 11, nn = m & 2047;
          if (n0 < 1024) {
            int h = n >> 6, d = n & 63;
            q_ws[(((size_t)bb * 16 + h) * 2048 + nn) * 64 + d] = (_Float16)(val * QSCALE);
          } else {
            int c = n - 1024, h = c >> 6, d = c & 63;
            k_ws[(((size_t)bb * 16 + h) * 2048 + nn) * 64 + d] = (_Float16)val;
          }
        }
      }
    }
  } else {
    #pragma unroll
    for (int it = 0; it < 4; it++) {
      #pragma unroll
      for (int jt = 0; jt < 4; jt++) {
        #pragma unroll
        for (int r = 0; r < 4; r++) {
          int ml = wr + it * 16 + qd * 4 + r;
          int nl = wc + jt * 16 + l15;
          Tt[nl * 136 + ml] = (_Float16)acc[it][jt][r];
        }
      }
    }
    __syncthreads();
    int row = tid >> 1;
    int mh  = (tid & 1) * 64;
    int c   = (n0 - 2048) + row;
    int bb  = m0 >> 11;
    int nnb = (m0 & 2047) + mh;
    _Float16* dstp =
        vT_ws + (((size_t)bb * 16 + (c >> 6)) * 64 + (c & 63)) * 2048 + nnb;
    #pragma unroll
    for (int i = 0; i < 8; i++)
      *(half8v*)(dstp + i * 8) = *(half8v*)&Tt[row * 136 + mh + i * 8];
  }
}

// ---------------------------------------------------------------------------
// Kernel 2: flash attention v17 (best measured: 54.0us) — v11 dataflow +
// software-pipelined softmax. Wave-private barrier-free counted-vmcnt loop;
// K/V double-buffered; iter i computes QK(i) while exp2/pack/PV run on
// s(i-1). Block->bh mapping is implicitly XCD-grouped (id&7 -> bh low bits
// -> 4 K/V streams = 2MB per XCD L2). v18's kf-preread variant SPILLED
// (WRITE_SIZE 8.2->16.1MB) — do not re-add register K prefetch.
// ---------------------------------------------------------------------------
__global__ __launch_bounds__(256, 2) void attn_kernel(
    const _Float16* __restrict__ q_ws, const _Float16* __restrict__ k_ws,
    const _Float16* __restrict__ vT_ws, _Float16* __restrict__ aout)
{
  constexpr int N = 2048;
  // 80KB: K [4w][2][2048] 32KB | V [4w][2][2048] 32KB | PQ [4w][2048] 16KB
  // Epilogue overlay: sc [4][64][64] f32 = 64KB at base; ls_sc 1KB at 65536.
  __shared__ alignas(16) char smem[81920];
  _Float16* Kbase = (_Float16*)smem;                  // 32KB
  _Float16* Vbase = (_Float16*)(smem + 32768);        // 32KB
  _Float16* PQ    = (_Float16*)(smem + 65536);        // 16KB

  const int id = blockIdx.x;
  const int bh = ((id >> 8) << 3) | (id & 7);
  const int qt = (id >> 3) & 31;

  const _Float16* Qp = q_ws + (size_t)bh * N * 64;
  const _Float16* Kp = k_ws + (size_t)bh * N * 64;
  const _Float16* Vp = vT_ws + (size_t)bh * 64 * N;

  const int tid = threadIdx.x, wave = tid >> 6, lane = tid & 63;
  const int qd = lane >> 4, l15 = lane & 15;
  const int q0 = qt * 64;
  const int wkv = wave * 32;        // this wave's kv offset within a stride

  _Float16* Ps = PQ + wave * 2048;          // private P slot (4KB)

  // per-wave staging lane constants
  const int krr = lane >> 3, kcb = (lane & 7) ^ krr;               // K staging
  const int vrr = lane >> 2, vcb = (lane & 3) ^ ((lane >> 3) & 3); // V staging

  auto stage_k = [&](int il, int buf) {
    const _Float16* src = Kp + (size_t)(wkv + il * 128) * 64;
    _Float16* dst = Kbase + (wave * 2 + buf) * 2048;
    #pragma unroll
    for (int j = 0; j < 4; j++)
      gld_lds16(src + (size_t)(j * 8 + krr) * 64 + kcb * 8,
                dst + (j * 64 + lane) * 8);
  };
  auto stage_v = [&](int il, int buf) {
    const _Float16* src = Vp + wkv + il * 128;
    _Float16* dst = Vbase + (wave * 2 + buf) * 2048;
    #pragma unroll
    for (int j = 0; j < 4; j++)
      gld_lds16(src + (size_t)(j * 16 + vrr) * N + vcb * 8,
                dst + (j * 64 + lane) * 8);
  };

  // Prologue (issue order: Q, K0, K1, V0 — the ledger depends on it).
  #pragma unroll
  for (int i = 0; i < 2; i++) {
    int idx = tid + i * 256;
    int r = idx >> 3, cb = (idx ^ r) & 7;
    gld_lds16(Qp + (size_t)(q0 + r) * 64 + cb * 8, PQ + idx * 8);
  }
  stage_k(0, 0);
  stage_k(1, 1);
  stage_v(0, 0);

  asm volatile("s_waitcnt vmcnt(12)" ::: "memory");   // own Q portion done
  __builtin_amdgcn_s_barrier();                       // Q resident (all waves)
  __builtin_amdgcn_sched_barrier(0);

  half8v qf[4][2];
  #pragma unroll
  for (int m = 0; m < 4; m++)
    #pragma unroll
    for (int ks = 0; ks < 2; ks++)
      qf[m][ks] = *(half8v*)&PQ[swz(m * 16 + l15, ks * 4 + qd)];

  asm volatile("s_waitcnt lgkmcnt(0)" ::: "memory");  // qf in regs
  __builtin_amdgcn_s_barrier();                       // before P overwrites Q
  __builtin_amdgcn_sched_barrier(0);

  const half8v ones = {(_Float16)1, (_Float16)1, (_Float16)1, (_Float16)1,
                       (_Float16)1, (_Float16)1, (_Float16)1, (_Float16)1};
  floatx4 o[4][4] = {};
  floatx4 ol[4] = {};
  floatx4 sA[2][4], sB[2][4];

  // QK phase: wait K(i), read kf, refill K(i+2), MFMA into scur.
  auto qk_step = [&](int i, floatx4 (&scur)[2][4]) {
    if (i >= 1 && i <= 14) asm volatile("s_waitcnt vmcnt(12)" ::: "memory");
    else                   asm volatile("s_waitcnt vmcnt(8)"  ::: "memory");
    __builtin_amdgcn_sched_barrier(0);
    const _Float16* Kb = Kbase + (wave * 2 + (i & 1)) * 2048;
    half8v kf[2][2];
    #pragma unroll
    for (int ks = 0; ks < 2; ks++) {
      kf[ks][0] = *(half8v*)&Kb[swz(l15, ks * 4 + qd)];
      kf[ks][1] = *(half8v*)&Kb[swz(16 + l15, ks * 4 + qd)];
    }
    asm volatile("s_waitcnt lgkmcnt(0)" ::: "memory");  // kf in regs (WAR)
    __builtin_amdgcn_sched_barrier(0);
    if (i <= 13) stage_k(i + 2, i & 1);
    __builtin_amdgcn_sched_barrier(0);
    #pragma unroll
    for (int nt = 0; nt < 2; nt++)
      #pragma unroll
      for (int m = 0; m < 4; m++)
        scur[nt][m] = floatx4{0.f, 0.f, 0.f, 0.f};
    __builtin_amdgcn_s_setprio(1);
    #pragma unroll
    for (int ks = 0; ks < 2; ks++)
      #pragma unroll
      for (int m = 0; m < 4; m++) {
        scur[0][m] = MFMA16(kf[ks][0], qf[m][ks], scur[0][m]);
        scur[1][m] = MFMA16(kf[ks][1], qf[m][ks], scur[1][m]);
      }
    __builtin_amdgcn_s_setprio(0);
  };

  // SM+PV phase for tile i-1: exp2(s_prev)->P, wait V(i-1), refill V(i+1), PV.
  auto sm_pv_step = [&](int i, floatx4 (&sprev)[2][4]) {
    #pragma unroll
    for (int m = 0; m < 4; m++)
      #pragma unroll
      for (int nt = 0; nt < 2; nt++) {
        float p0 = __builtin_amdgcn_exp2f(sprev[nt][m][0]);
        float p1 = __builtin_amdgcn_exp2f(sprev[nt][m][1]);
        float p2 = __builtin_amdgcn_exp2f(sprev[nt][m][2]);
        float p3 = __builtin_amdgcn_exp2f(sprev[nt][m][3]);
        half2v h01 = pk16(p0, p1);
        half2v h23 = pk16(p2, p3);
        half4v pk;
        pk[0] = h01[0]; pk[1] = h01[1]; pk[2] = h23[0]; pk[3] = h23[1];
        *(half4v*)&Ps[vswz(m * 16 + l15, 2 * nt + (qd >> 1)) + (qd & 1) * 4] = pk;
      }
    half8v pf[4], vfr[4];
    #pragma unroll
    for (int m = 0; m < 4; m++)
      pf[m] = *(half8v*)&Ps[vswz(m * 16 + l15, qd)];
    if (i <= 13)       asm volatile("s_waitcnt vmcnt(12)" ::: "memory");
    else if (i == 14)  asm volatile("s_waitcnt vmcnt(8)"  ::: "memory");
    else if (i == 15)  asm volatile("s_waitcnt vmcnt(4)"  ::: "memory");
    else               asm volatile("s_waitcnt vmcnt(0)"  ::: "memory");
    __builtin_amdgcn_sched_barrier(0);
    const _Float16* Vb = Vbase + (wave * 2 + ((i - 1) & 1)) * 2048;
    #pragma unroll
    for (int dt = 0; dt < 4; dt++)
      vfr[dt] = *(half8v*)&Vb[vswz(dt * 16 + l15, qd)];
    asm volatile("s_waitcnt lgkmcnt(0)" ::: "memory");  // reads done (WAR)
    __builtin_amdgcn_sched_barrier(0);
    if (i <= 14) stage_v(i + 1, (i + 1) & 1);
    __builtin_amdgcn_sched_barrier(0);
    __builtin_amdgcn_s_setprio(1);
    #pragma unroll
    for (int m = 0; m < 4; m++)
      ol[m] = MFMA16(pf[m], ones, ol[m]);
    #pragma unroll
    for (int m = 0; m < 4; m++)
      #pragma unroll
      for (int dt = 0; dt < 4; dt++)
        o[m][dt] = MFMA16(pf[m], vfr[dt], o[m][dt]);
    __builtin_amdgcn_s_setprio(0);
  };

  // iter 0 peeled: QK(0)->sA, then issue V1.
  qk_step(0, sA);
  stage_v(1, 1);

  // iters 1..15, paired so s-arrays alternate without copies.
  for (int i = 1; i <= 15; i += 2) {
    qk_step(i, sB);
    sm_pv_step(i, sA);
    if (i + 1 <= 15) {
      qk_step(i + 1, sA);
      sm_pv_step(i + 1, sB);
    }
  }
  // tail: softmax+PV of tile 15 (held in sB since 15 is odd).
  sm_pv_step(16, sB);

  // ---- epilogue: cross-wave reduction of O and lsum via (dead) LDS ----
  __syncthreads();
  float* sc    = (float*)smem;            // [4][64][64] f32 partials (64KB)
  float* ls_sc = (float*)(smem + 65536);  // [4][64] f32 lsums (1KB)
  float* myp = sc + wave * 4096;
  #pragma unroll
  for (int m = 0; m < 4; m++)
    #pragma unroll
    for (int r = 0; r < 4; r++) {
      int row = m * 16 + qd * 4 + r;
      myp[row * 64 +  0 + l15] = o[m][0][r];
      myp[row * 64 + 16 + l15] = o[m][1][r];
      myp[row * 64 + 32 + l15] = o[m][2][r];
      myp[row * 64 + 48 + l15] = o[m][3][r];
      ls_sc[wave * 64 + row] = ol[m][r];  // same value from 16 lanes, one wins
    }
  __syncthreads();

  const int bb = bh >> 4, hh = bh & 15;
  #pragma unroll
  for (int j = 0; j < 4; j++) {
    int row = wave * 16 + j * 4 + qd;
    floatx4 a0 = *(floatx4*)&sc[(size_t)(0 * 64 + row) * 64 + l15 * 4];
    floatx4 a1 = *(floatx4*)&sc[(size_t)(1 * 64 + row) * 64 + l15 * 4];
    floatx4 a2 = *(floatx4*)&sc[(size_t)(2 * 64 + row) * 64 + l15 * 4];
    floatx4 a3 = *(floatx4*)&sc[(size_t)(3 * 64 + row) * 64 + l15 * 4];
    floatx4 sum = (a0 + a1) + (a2 + a3);
    float ls = ls_sc[row] + ls_sc[64 + row] + ls_sc[128 + row] + ls_sc[192 + row];
    float inv = 1.0f / ls;
    half2v h01 = pk16(sum[0] * inv, sum[1] * inv);
    half2v h23 = pk16(sum[2] * inv, sum[3] * inv);
    half4v hv;
    hv[0] = h01[0]; hv[1] = h01[1]; hv[2] = h23[0]; hv[3] = h23[1];
    *(half4v*)(aout + ((size_t)(bb * 2048 + q0 + row)) * 1024 + hh * 64 + l15 * 4) = hv;
  }
}

// ---------------------------------------------------------------------------
// Kernel 3: out projection — BK=64 (R6 win) + T1 XCD swizzle (bijective
// 512=8*64; bx-major so each XCD keeps 8 A-panels = 1MB L2-hot, B = 2MB).
// ---------------------------------------------------------------------------
__global__ __launch_bounds__(256) void out_gemm(
    const _Float16* __restrict__ A, const _Float16* __restrict__ WoT,
    const float* __restrict__ bo, float* __restrict__ Out)
{
  constexpr int K = 1024;
  __shared__ alignas(16) _Float16 As[64 * 64];    // 8 KB
  __shared__ alignas(16) _Float16 Bs[128 * 64];   // 16 KB

  const int id = blockIdx.y * 64 + blockIdx.x;
  const int w  = (id & 7) * 64 + (id >> 3);   // XCD-contiguous work id
  const int m0 = (w >> 3) * 64;
  const int n0 = (w & 7) * 128;
  const int tid = threadIdx.x;
  const int wave = tid >> 6, lane = tid & 63;
  const int qd = lane >> 4, l15 = lane & 15;
  const int wr = (wave >> 1) * 32, wc = (wave & 1) * 64;

  floatx4 acc[2][4] = {};

  for (int k0 = 0; k0 < K; k0 += 64) {
    #pragma unroll
    for (int i = 0; i < 2; i++) {
      int idx = tid + i * 256;
      int r = idx >> 3, cb = (idx ^ r) & 7;
      gld_lds16(A + (size_t)(m0 + r) * K + k0 + cb * 8, &As[idx * 8]);
    }
    #pragma unroll
    for (int i = 0; i < 4; i++) {
      int idx = tid + i * 256;
      int r = idx >> 3, cb = (idx ^ r) & 7;
      gld_lds16(WoT + (size_t)(n0 + r) * K + k0 + cb * 8, &Bs[idx * 8]);
    }
    __syncthreads();
    half8v a[2][2], b[4][2];
    #pragma unroll
    for (int it = 0; it < 2; it++)
      #pragma unroll
      for (int ks = 0; ks < 2; ks++)
        a[it][ks] = *(half8v*)&As[swz(wr + it * 16 + l15, ks * 4 + qd)];
    #pragma unroll
    for (int jt = 0; jt < 4; jt++)
      #pragma unroll
      for (int ks = 0; ks < 2; ks++)
        b[jt][ks] = *(half8v*)&Bs[swz(wc + jt * 16 + l15, ks * 4 + qd)];
    #pragma unroll
    for (int ks = 0; ks < 2; ks++)
      #pragma unroll
      for (int it = 0; it < 2; it++)
        #pragma unroll
        for (int jt = 0; jt < 4; jt++)
          acc[it][jt] = MFMA16(a[it][ks], b[jt][ks], acc[it][jt]);
    __syncthreads();
  }

  #pragma unroll
  for (int it = 0; it < 2; it++) {
    #pragma unroll
    for (int jt = 0; jt < 4; jt++) {
      int n = n0 + wc + jt * 16 + l15;
      float bias = bo[n];
      #pragma unroll
      for (int r = 0; r < 4; r++) {
        int m = m0 + wr + it * 16 + qd * 4 + r;
        Out[(size_t)m * 1024 + n] = acc[it][jt][r] + bias;
      }
    }
  }
}

// ---------------------------------------------------------------------------
extern "C" void kernel_launch(void* const* d_in, const int* in_sizes, int n_in,
                              void* d_out, int out_size, void* d_ws, size_t ws_size,
                              hipStream_t stream) {
  const float* X   = (const float*)d_in[0];
  const float* Wq  = (const float*)d_in[1];
  const float* Wkv = (const float*)d_in[2];
  const float* Wo  = (const float*)d_in[3];
  const float* bo  = (const float*)d_in[4];
  float* out = (float*)d_out;

  const size_t M4 = (size_t)4 * 1024 * 1024;
  _Float16* q_ws   = (_Float16*)d_ws;
  _Float16* k_ws   = q_ws + M4;
  _Float16* vT_ws  = k_ws + M4;
  _Float16* X16    = vT_ws + M4;
  _Float16* WqkvT  = X16 + M4;
  _Float16* WoT    = WqkvT + (size_t)3 * 1024 * 1024;
  _Float16* aout   = X16;  // X16 dead after qkv_gemm

  prep<<<3072, 256, 0, stream>>>(X, Wq, Wkv, Wo, X16, WqkvT, WoT);
  qkv_gemm<<<dim3(32, 24), 256, 0, stream>>>(X16, WqkvT, q_ws, k_ws, vT_ws);
  attn_kernel<<<1024, 256, 0, stream>>>(q_ws, k_ws, vT_ws, aout);
  out_gemm<<<dim3(64, 8), 256, 0, stream>>>(aout, WoT, bo, out);
}